// Round 5
// baseline (473.226 us; speedup 1.0000x reference)
//
#include <hip/hip_runtime.h>
#include <stdint.h>

typedef __attribute__((ext_vector_type(8))) short short8;
typedef __attribute__((ext_vector_type(4))) float f32x4;
typedef unsigned short u16;
typedef unsigned int u32;

#define NTOK 4096   // B*S
#define E 2048
#define S 2048
#define NH 16
#define NKVH 4
#define HD 128
#define NQKV 3072   // E + 512 + 512

__device__ __forceinline__ float bf2f(u16 u) {
    return __uint_as_float(((u32)u) << 16);
}
__device__ __forceinline__ u16 f2bf(float f) {
    u32 u = __float_as_uint(f);
    u32 r = (u + 0x7fffu + ((u >> 16) & 1u)) >> 16;
    return (u16)r;
}
__device__ __forceinline__ void gload_lds16(const u16* g, u16* l) {
    __builtin_amdgcn_global_load_lds(
        (const __attribute__((address_space(1))) unsigned int*)(g),
        (__attribute__((address_space(3))) unsigned int*)(l), 16, 0, 0);
}

// ---------------- fused fp32 -> bf16 cast of all 5 tensors ----------------
// Wqkv layout: rows 0..2047 = Wq, 2048..2559 = Wk, 2560..3071 = Wv
__global__ void cast5(const float* __restrict__ x, const float* __restrict__ wq,
                      const float* __restrict__ wk, const float* __restrict__ wv,
                      const float* __restrict__ wo,
                      u16* __restrict__ xb, u16* __restrict__ wqkvb,
                      u16* __restrict__ wob) {
    int i = blockIdx.x * 256 + threadIdx.x;
    const float* s; u16* d; int rel;
    if (i < 2097152)      { s = x;  d = xb;  rel = i; }
    else if (i < 3145728) { s = wq; d = wqkvb; rel = i - 2097152; }
    else if (i < 3407872) { s = wk; d = wqkvb + 4194304; rel = i - 3145728; }
    else if (i < 3670016) { s = wv; d = wqkvb + 5242880; rel = i - 3407872; }
    else                  { s = wo; d = wob; rel = i - 3670016; }
    float4 v = *(const float4*)(s + (size_t)rel * 4);
    ushort4 o;
    o.x = f2bf(v.x); o.y = f2bf(v.y); o.z = f2bf(v.z); o.w = f2bf(v.w);
    *(ushort4*)(d + (size_t)rel * 4) = o;
}

// ---------------- bf16 GEMM, C[M,N] = A[M,K] * Bt[N,K]^T, m97-style async staging ----------
#define TM 128
#define TN 128
#define BK 64

__global__ __launch_bounds__(256, 3)
void gemm_bt(const u16* __restrict__ A, const u16* __restrict__ Bt, float* __restrict__ C,
             int M, int N, int K) {
    __shared__ u16 As[TM * BK];
    __shared__ u16 Bs[TN * BK];
    const int m0 = blockIdx.y * TM;
    const int n0 = blockIdx.x * TN;
    const int tid = threadIdx.x;
    const int w = tid >> 6, lane = tid & 63;
    const int wm = (w >> 1) * 64, wn = (w & 1) * 64;
    const int lr = lane & 15, quad = lane >> 4;

    f32x4 acc[4][4];
#pragma unroll
    for (int mi = 0; mi < 4; mi++)
#pragma unroll
        for (int ni = 0; ni < 4; ni++)
            acc[mi][ni] = (f32x4){0.f, 0.f, 0.f, 0.f};

    const int srow = w * 8 + (lane >> 3);
    const int scol = (lane & 7) * 8;
    const u16* ga0 = A + (size_t)(m0 + srow) * K + scol;
    const u16* gb0 = Bt + (size_t)(n0 + srow) * K + scol;

    for (int kt = 0; kt < K; kt += BK) {
        __syncthreads();
#pragma unroll
        for (int i = 0; i < 4; i++) {
            gload_lds16(ga0 + (size_t)(i * 32) * K + kt, &As[(w * 8 + i * 32) * BK]);
            gload_lds16(gb0 + (size_t)(i * 32) * K + kt, &Bs[(w * 8 + i * 32) * BK]);
        }
        __syncthreads();
#pragma unroll
        for (int kk = 0; kk < BK; kk += 32) {
            const int ko = kk + quad * 8;
            short8 af[4], bfr[4];
#pragma unroll
            for (int mi = 0; mi < 4; mi++)
                af[mi] = *(const short8*)(&As[(wm + mi * 16 + lr) * BK + ko]);
#pragma unroll
            for (int ni = 0; ni < 4; ni++)
                bfr[ni] = *(const short8*)(&Bs[(wn + ni * 16 + lr) * BK + ko]);
#pragma unroll
            for (int mi = 0; mi < 4; mi++)
#pragma unroll
                for (int ni = 0; ni < 4; ni++)
                    acc[mi][ni] = __builtin_amdgcn_mfma_f32_16x16x32_bf16(
                        af[mi], bfr[ni], acc[mi][ni], 0, 0, 0);
        }
    }
#pragma unroll
    for (int mi = 0; mi < 4; mi++)
#pragma unroll
        for (int ni = 0; ni < 4; ni++) {
            int row = m0 + wm + mi * 16 + quad * 4;
            int col = n0 + wn + ni * 16 + lr;
            f32x4 v = acc[mi][ni];
            C[(size_t)(row + 0) * N + col] = v[0];
            C[(size_t)(row + 1) * N + col] = v[1];
            C[(size_t)(row + 2) * N + col] = v[2];
            C[(size_t)(row + 3) * N + col] = v[3];
        }
}

// ---------------- RMSNorm + RoPE for BOTH q and k in one dispatch ----------------
// reads from merged qkvraw [NTOK, 3072]: q at col 0, k at col 2048
__global__ __launch_bounds__(256)
void rmsrope2(const float* __restrict__ qkv,
              const float* __restrict__ qw, const float* __restrict__ kw,
              u16* __restrict__ qdst, u16* __restrict__ kdst) {
    int p = blockIdx.x * 4 + (threadIdx.x >> 6);
    int lane = threadIdx.x & 63;
    const float* src; const float* w; u16* dst; int HH;
    if (p < NTOK * NH) { src = qkv; w = qw; dst = qdst; HH = NH; }
    else { p -= NTOK * NH; src = qkv + 2048; w = kw; dst = kdst; HH = NKVH; }
    int n = p / HH;
    int h = p - n * HH;
    int b = n >> 11;
    int s = n & 2047;
    const float* row = src + (size_t)n * NQKV + h * HD;
    float t1 = row[lane];
    float t2 = row[lane + 64];
    float ss = t1 * t1 + t2 * t2;
#pragma unroll
    for (int o = 1; o < 64; o <<= 1) ss += __shfl_xor(ss, o);
    float r = rsqrtf(ss * (1.f / 128.f) + 1e-6f);
    float a1 = t1 * r * w[lane];
    float a2 = t2 * r * w[lane + 64];
    float freq = expf(lane * -0.14391156831212787f);
    float ang = (float)s * freq;
    float sn, cs;
    sincosf(ang, &sn, &cs);
    float o1 = a1 * cs - a2 * sn;
    float o2 = a2 * cs + a1 * sn;
    size_t base = (((size_t)(b * HH + h)) * S + s) * HD;
    dst[base + lane] = f2bf(o1);
    dst[base + 64 + lane] = f2bf(o2);
}

// ---------------- V: cast + transpose (n, 2560 + kh*D+d of qkv) fp32 -> Vt (b,kh,d,s) bf16 --
#define LDT 65
__global__ __launch_bounds__(256)
void vtrans(const float* __restrict__ src, u16* __restrict__ dst) {
    __shared__ u16 Ts[128 * LDT];
    const int t = threadIdx.x;
    const int s0 = blockIdx.x * 64;
    const int kh = blockIdx.y;
    const int b = blockIdx.z;
    const float* base = src + ((size_t)(b * S + s0)) * NQKV + 2560 + kh * HD;
#pragma unroll
    for (int i = 0; i < 8; i++) {
        int idx = i * 256 + t;
        int r = idx >> 5, c4 = (idx & 31) * 4;
        float4 v = *(const float4*)(base + (size_t)r * NQKV + c4);
        Ts[(c4 + 0) * LDT + r] = f2bf(v.x);
        Ts[(c4 + 1) * LDT + r] = f2bf(v.y);
        Ts[(c4 + 2) * LDT + r] = f2bf(v.z);
        Ts[(c4 + 3) * LDT + r] = f2bf(v.w);
    }
    __syncthreads();
    u16* obase = dst + ((size_t)(b * NKVH + kh) * HD) * S + s0;
#pragma unroll
    for (int i = 0; i < 4; i++) {
        int idx = i * 256 + t;
        int d = idx >> 3, s8 = (idx & 7) * 8;
        const u16* row = &Ts[d * LDT + s8];
        short8 o;
#pragma unroll
        for (int j = 0; j < 8; j++) o[j] = (short)row[j];
        *(short8*)(obase + (size_t)d * S + s8) = o;
    }
}

// ---------------- MFMA flash attention, 128-query blocks, XOR-swizzled LDS ----------------
// block: 128 queries x 1 head; 4 waves x 32 queries (two 16-q groups per wave)
// LDS: Ks 16KB + Vs 16KB + Ps 16KB = 49152 B -> 3 blocks/CU
#define KSX(key, cb) ((key) * 128 + ((((cb) ^ ((key) & 15))) * 8))
#define VSX(d, cb)   ((d) * 64 + ((((cb) ^ ((d) & 7))) * 8))
#define PSX(row, cb) ((row) * 64 + ((((cb) ^ ((row) & 7))) * 8))

__global__ __launch_bounds__(256, 3)
void attn_mfma(const u16* __restrict__ qa, const u16* __restrict__ ka,
               const u16* __restrict__ vt, u16* __restrict__ out) {
    __shared__ u16 Ks[64 * 128];
    __shared__ u16 Vs[128 * 64];
    __shared__ u16 Ps[128 * 64];
    const int tid = threadIdx.x;
    const int w = tid >> 6, lane = tid & 63;
    const int lr = lane & 15, quad = lane >> 4;
    const int qt = (int)(gridDim.x - 1) - blockIdx.x;   // heavy blocks first
    const int h = blockIdx.y, b = blockIdx.z;
    const int kh = h >> 2;
    const int q0 = qt * 128;
    const int qg0 = q0 + w * 32;          // group gi: queries qg0+gi*16 .. +15

    const float SCINV = 0.0017677669529663689f;  // 1/(sqrt(128)*50)

    short8 qf[2][4];
#pragma unroll
    for (int gi = 0; gi < 2; gi++) {
        const u16* qrow = qa + (((size_t)(b * NH + h)) * S + qg0 + gi * 16 + lr) * HD;
#pragma unroll
        for (int c = 0; c < 4; c++)
            qf[gi][c] = *(const short8*)(qrow + c * 32 + quad * 8);
    }

    f32x4 O[2][8];
#pragma unroll
    for (int gi = 0; gi < 2; gi++)
#pragma unroll
        for (int dt = 0; dt < 8; dt++) O[gi][dt] = (f32x4){0.f, 0.f, 0.f, 0.f};
    float l[2][4] = {{0.f, 0.f, 0.f, 0.f}, {0.f, 0.f, 0.f, 0.f}};

    const u16* kbase0 = ka + (((size_t)(b * NKVH + kh)) * S) * HD;
    const u16* vtbase0 = vt + ((size_t)(b * NKVH + kh) * HD) * S;

    const int jt0 = (q0 >= 1024) ? (q0 - 1024) : 0;
    const int jtend = q0 + 64;           // inclusive; upper half's diagonal tile
    for (int jt = jt0; jt <= jtend; jt += 64) {
        __syncthreads();
        const u16* kbase = kbase0 + (size_t)jt * HD;
        const u16* vtbase = vtbase0 + jt;
#pragma unroll
        for (int i = 0; i < 4; i++) {
            int idx = i * 256 + tid;
            int key = idx >> 4, cb = idx & 15;
            *(int4*)(&Ks[KSX(key, cb)]) = *(const int4*)(kbase + (size_t)key * HD + cb * 8);
            int dd = idx >> 3, cb2 = idx & 7;
            *(int4*)(&Vs[VSX(dd, cb2)]) = *(const int4*)(vtbase + (size_t)dd * S + cb2 * 8);
        }
        __syncthreads();

        u16* Pw = &Ps[w * 32 * 64];      // local rows 0..31
        bool any0 = false, any1 = false;

#pragma unroll
        for (int kt = 0; kt < 4; kt++) {
            const int keymin = jt + kt * 16;
            bool need[2], full[2];
#pragma unroll
            for (int gi = 0; gi < 2; gi++) {
                int qmin = qg0 + gi * 16, qmax = qmin + 15;
                need[gi] = (keymin <= qmax) && (keymin + 15 >= qmin - 1023);
                full[gi] = (keymin + 15 <= qmin) && (keymin >= qmax - 1023);
            }
            if (need[0] || need[1]) {
                short8 kf[4];
#pragma unroll
                for (int c = 0; c < 4; c++)
                    kf[c] = *(const short8*)(&Ks[KSX(kt * 16 + lr, 4 * c + quad)]);
#pragma unroll
                for (int gi = 0; gi < 2; gi++) {
                    if (need[gi]) {
                        f32x4 a = (f32x4){0.f, 0.f, 0.f, 0.f};
#pragma unroll
                        for (int c = 0; c < 4; c++)
                            a = __builtin_amdgcn_mfma_f32_16x16x32_bf16(qf[gi][c], kf[c], a, 0, 0, 0);
#pragma unroll
                        for (int r = 0; r < 4; r++) {
                            // p = exp(sc - 50), sc = 50*tanh(x) => p = exp(-100/(e^{2x}+1))
                            float x = a[r] * SCINV;
                            float t = __expf(2.f * x);
                            float p = __expf(-100.f * __builtin_amdgcn_rcpf(t + 1.f));
                            if (!full[gi]) {
                                int rel = keymin + lr - (qg0 + gi * 16 + quad * 4 + r);
                                bool valid = (rel <= 0) && (rel > -1024);
                                p = valid ? p : 0.f;
                            }
                            l[gi][r] += p;
                            Pw[PSX(gi * 16 + quad * 4 + r, kt * 2 + (lr >> 3)) + (lr & 7)] =
                                (u16)(__float_as_uint(p) >> 16);
                        }
                        if (gi == 0) any0 = true; else any1 = true;
                    } else {
#pragma unroll
                        for (int r = 0; r < 4; r++)
                            Pw[PSX(gi * 16 + quad * 4 + r, kt * 2 + (lr >> 3)) + (lr & 7)] = 0;
                    }
                }
            } else {
#pragma unroll
                for (int gi = 0; gi < 2; gi++)
#pragma unroll
                    for (int r = 0; r < 4; r++)
                        Pw[PSX(gi * 16 + quad * 4 + r, kt * 2 + (lr >> 3)) + (lr & 7)] = 0;
            }
        }

        // PV: O[q][d] += P[q][key] * Vt[d][key]   (vf shared across both q-groups)
        if (any0 || any1) {
#pragma unroll
            for (int c2 = 0; c2 < 2; c2++) {
                short8 vf[8];
#pragma unroll
                for (int dt = 0; dt < 8; dt++)
                    vf[dt] = *(const short8*)(&Vs[VSX(dt * 16 + lr, c2 * 4 + quad)]);
#pragma unroll
                for (int gi = 0; gi < 2; gi++) {
                    if (gi == 0 ? !any0 : !any1) continue;
                    short8 pf = *(const short8*)(&Pw[PSX(gi * 16 + lr, c2 * 4 + quad)]);
#pragma unroll
                    for (int dt = 0; dt < 8; dt++)
                        O[gi][dt] = __builtin_amdgcn_mfma_f32_16x16x32_bf16(pf, vf[dt], O[gi][dt], 0, 0, 0);
                }
            }
        }
    }

#pragma unroll
    for (int gi = 0; gi < 2; gi++)
#pragma unroll
        for (int r = 0; r < 4; r++) {
            l[gi][r] += __shfl_xor(l[gi][r], 1);
            l[gi][r] += __shfl_xor(l[gi][r], 2);
            l[gi][r] += __shfl_xor(l[gi][r], 4);
            l[gi][r] += __shfl_xor(l[gi][r], 8);
        }
#pragma unroll
    for (int gi = 0; gi < 2; gi++)
#pragma unroll
        for (int r = 0; r < 4; r++) {
            float inv = 1.f / l[gi][r];
            u16* orow = out + ((size_t)(b * S + qg0 + gi * 16 + quad * 4 + r)) * E + h * HD;
#pragma unroll
            for (int dt = 0; dt < 8; dt++)
                orow[dt * 16 + lr] = f2bf(O[gi][dt][r] * inv);
        }
}

// ---------------- residual + LayerNorm ----------------
__global__ __launch_bounds__(256)
void ln_kernel(const float* __restrict__ x, const float* __restrict__ pr,
               const float* __restrict__ g, const float* __restrict__ be,
               float* __restrict__ out) {
    int n = blockIdx.x;
    int tid = threadIdx.x;
    const float* xr = x + (size_t)n * E;
    const float* p = pr + (size_t)n * E;
    float y[8];
    float s = 0.f, ss = 0.f;
#pragma unroll
    for (int i = 0; i < 2; i++) {
        float4 a = *(const float4*)(xr + tid * 8 + i * 4);
        float4 b = *(const float4*)(p + tid * 8 + i * 4);
        float v0 = a.x + b.x, v1 = a.y + b.y, v2 = a.z + b.z, v3 = a.w + b.w;
        y[i * 4 + 0] = v0; y[i * 4 + 1] = v1; y[i * 4 + 2] = v2; y[i * 4 + 3] = v3;
        s += v0 + v1 + v2 + v3;
        ss += v0 * v0 + v1 * v1 + v2 * v2 + v3 * v3;
    }
#pragma unroll
    for (int o = 1; o < 64; o <<= 1) {
        s += __shfl_xor(s, o);
        ss += __shfl_xor(ss, o);
    }
    __shared__ float r0[4], r1[4];
    int w = tid >> 6;
    if ((tid & 63) == 0) { r0[w] = s; r1[w] = ss; }
    __syncthreads();
    s = r0[0] + r0[1] + r0[2] + r0[3];
    ss = r1[0] + r1[1] + r1[2] + r1[3];
    float mu = s * (1.f / 2048.f);
    float var = ss * (1.f / 2048.f) - mu * mu;
    float rs = rsqrtf(var + 1e-5f);
    float* orow = out + (size_t)n * E;
#pragma unroll
    for (int i = 0; i < 8; i++) {
        int c = tid * 8 + i;
        orow[c] = (y[i] - mu) * rs * g[c] + be[c];
    }
}

// ---------------- launch ----------------
extern "C" void kernel_launch(void* const* d_in, const int* in_sizes, int n_in,
                              void* d_out, int out_size, void* d_ws, size_t ws_size,
                              hipStream_t stream) {
    (void)in_sizes; (void)n_in; (void)out_size; (void)ws_size;
    const float* x   = (const float*)d_in[0];
    const float* Wq  = (const float*)d_in[1];
    const float* Wk  = (const float*)d_in[2];
    const float* Wv  = (const float*)d_in[3];
    const float* Wo  = (const float*)d_in[4];
    const float* qnw = (const float*)d_in[5];
    const float* knw = (const float*)d_in[6];
    const float* lng = (const float*)d_in[7];
    const float* lnb = (const float*)d_in[8];
    float* out = (float*)d_out;

    char* ws = (char*)d_ws;
    size_t off = 0;
    auto alloc = [&](size_t bytes) -> char* {
        char* pp = ws + off;
        off = (off + bytes + 255) & ~(size_t)255;
        return pp;
    };
    u16*  xb     = (u16*)alloc((size_t)NTOK * E * 2);       // later reused as attn_out
    u16*  Wqkvb  = (u16*)alloc((size_t)NQKV * E * 2);       // [Wq; Wk; Wv]
    u16*  Wob    = (u16*)alloc((size_t)E * E * 2);
    float* qkvraw= (float*)alloc((size_t)NTOK * NQKV * 4);  // later reused as proj
    u16*  qaa    = (u16*)alloc((size_t)NTOK * E * 2);
    u16*  kaa    = (u16*)alloc((size_t)NTOK * 512 * 2);
    u16*  vtt    = (u16*)alloc((size_t)NTOK * 512 * 2);
    u16*  attn_o = xb;
    float* proj  = qkvraw;

    cast5<<<dim3(18432), 256, 0, stream>>>(x, Wq, Wk, Wv, Wo, xb, Wqkvb, Wob);

    gemm_bt<<<dim3(NQKV / TN, NTOK / TM), 256, 0, stream>>>(xb, Wqkvb, qkvraw, NTOK, NQKV, E);

    rmsrope2<<<dim3((NTOK * NH + NTOK * NKVH) / 4), 256, 0, stream>>>(
        qkvraw, qnw, knw, qaa, kaa);
    vtrans<<<dim3(S / 64, NKVH, 2), 256, 0, stream>>>(qkvraw, vtt);

    attn_mfma<<<dim3(S / 128, NH, 2), 256, 0, stream>>>(qaa, kaa, vtt, attn_o);

    gemm_bt<<<dim3(E / TN, NTOK / TM), 256, 0, stream>>>(attn_o, Wob, proj, NTOK, E, E);

    ln_kernel<<<dim3(NTOK), 256, 0, stream>>>(x, proj, lng, lnb, out);
}

// Round 6
// 356.050 us; speedup vs baseline: 1.3291x; 1.3291x over previous
//
#include <hip/hip_runtime.h>
#include <stdint.h>

typedef __attribute__((ext_vector_type(8))) short short8;
typedef __attribute__((ext_vector_type(4))) float f32x4;
typedef unsigned short u16;
typedef unsigned int u32;

#define NTOK 4096   // B*S
#define E 2048
#define S 2048
#define NH 16
#define NKVH 4
#define HD 128
#define NQKV 3072   // E + 512 + 512

__device__ __forceinline__ float bf2f(u16 u) {
    return __uint_as_float(((u32)u) << 16);
}
__device__ __forceinline__ u16 f2bf(float f) {
    u32 u = __float_as_uint(f);
    u32 r = (u + 0x7fffu + ((u >> 16) & 1u)) >> 16;
    return (u16)r;
}
__device__ __forceinline__ void gload_lds16(const u16* g, u16* l) {
    __builtin_amdgcn_global_load_lds(
        (const __attribute__((address_space(1))) unsigned int*)(g),
        (__attribute__((address_space(3))) unsigned int*)(l), 16, 0, 0);
}

// ---------------- fused fp32 -> bf16 cast of all 5 tensors ----------------
// Wqkv layout: rows 0..2047 = Wq, 2048..2559 = Wk, 2560..3071 = Wv
__global__ void cast5(const float* __restrict__ x, const float* __restrict__ wq,
                      const float* __restrict__ wk, const float* __restrict__ wv,
                      const float* __restrict__ wo,
                      u16* __restrict__ xb, u16* __restrict__ wqkvb,
                      u16* __restrict__ wob) {
    int i = blockIdx.x * 256 + threadIdx.x;
    const float* s; u16* d; int rel;
    if (i < 2097152)      { s = x;  d = xb;  rel = i; }
    else if (i < 3145728) { s = wq; d = wqkvb; rel = i - 2097152; }
    else if (i < 3407872) { s = wk; d = wqkvb + 4194304; rel = i - 3145728; }
    else if (i < 3670016) { s = wv; d = wqkvb + 5242880; rel = i - 3407872; }
    else                  { s = wo; d = wob; rel = i - 3670016; }
    float4 v = *(const float4*)(s + (size_t)rel * 4);
    ushort4 o;
    o.x = f2bf(v.x); o.y = f2bf(v.y); o.z = f2bf(v.z); o.w = f2bf(v.w);
    *(ushort4*)(d + (size_t)rel * 4) = o;
}

// ---------------- bf16 GEMM, C[M,N] = A[M,K] * Bt[N,K]^T, m97-style async staging ----------
#define TM 128
#define TN 128
#define BK 64

__global__ __launch_bounds__(256, 3)
void gemm_bt(const u16* __restrict__ A, const u16* __restrict__ Bt, float* __restrict__ C,
             int M, int N, int K) {
    __shared__ u16 As[TM * BK];
    __shared__ u16 Bs[TN * BK];
    const int m0 = blockIdx.y * TM;
    const int n0 = blockIdx.x * TN;
    const int tid = threadIdx.x;
    const int w = tid >> 6, lane = tid & 63;
    const int wm = (w >> 1) * 64, wn = (w & 1) * 64;
    const int lr = lane & 15, quad = lane >> 4;

    f32x4 acc[4][4];
#pragma unroll
    for (int mi = 0; mi < 4; mi++)
#pragma unroll
        for (int ni = 0; ni < 4; ni++)
            acc[mi][ni] = (f32x4){0.f, 0.f, 0.f, 0.f};

    const int srow = w * 8 + (lane >> 3);
    const int scol = (lane & 7) * 8;
    const u16* ga0 = A + (size_t)(m0 + srow) * K + scol;
    const u16* gb0 = Bt + (size_t)(n0 + srow) * K + scol;

    for (int kt = 0; kt < K; kt += BK) {
        __syncthreads();
#pragma unroll
        for (int i = 0; i < 4; i++) {
            gload_lds16(ga0 + (size_t)(i * 32) * K + kt, &As[(w * 8 + i * 32) * BK]);
            gload_lds16(gb0 + (size_t)(i * 32) * K + kt, &Bs[(w * 8 + i * 32) * BK]);
        }
        __syncthreads();
#pragma unroll
        for (int kk = 0; kk < BK; kk += 32) {
            const int ko = kk + quad * 8;
            short8 af[4], bfr[4];
#pragma unroll
            for (int mi = 0; mi < 4; mi++)
                af[mi] = *(const short8*)(&As[(wm + mi * 16 + lr) * BK + ko]);
#pragma unroll
            for (int ni = 0; ni < 4; ni++)
                bfr[ni] = *(const short8*)(&Bs[(wn + ni * 16 + lr) * BK + ko]);
#pragma unroll
            for (int mi = 0; mi < 4; mi++)
#pragma unroll
                for (int ni = 0; ni < 4; ni++)
                    acc[mi][ni] = __builtin_amdgcn_mfma_f32_16x16x32_bf16(
                        af[mi], bfr[ni], acc[mi][ni], 0, 0, 0);
        }
    }
#pragma unroll
    for (int mi = 0; mi < 4; mi++)
#pragma unroll
        for (int ni = 0; ni < 4; ni++) {
            int row = m0 + wm + mi * 16 + quad * 4;
            int col = n0 + wn + ni * 16 + lr;
            f32x4 v = acc[mi][ni];
            C[(size_t)(row + 0) * N + col] = v[0];
            C[(size_t)(row + 1) * N + col] = v[1];
            C[(size_t)(row + 2) * N + col] = v[2];
            C[(size_t)(row + 3) * N + col] = v[3];
        }
}

// ---------------- RMSNorm + RoPE for BOTH q and k in one dispatch ----------------
// reads from merged qkvraw [NTOK, 3072]: q at col 0, k at col 2048
__global__ __launch_bounds__(256)
void rmsrope2(const float* __restrict__ qkv,
              const float* __restrict__ qw, const float* __restrict__ kw,
              u16* __restrict__ qdst, u16* __restrict__ kdst) {
    int p = blockIdx.x * 4 + (threadIdx.x >> 6);
    int lane = threadIdx.x & 63;
    const float* src; const float* w; u16* dst; int HH;
    if (p < NTOK * NH) { src = qkv; w = qw; dst = qdst; HH = NH; }
    else { p -= NTOK * NH; src = qkv + 2048; w = kw; dst = kdst; HH = NKVH; }
    int n = p / HH;
    int h = p - n * HH;
    int b = n >> 11;
    int s = n & 2047;
    const float* row = src + (size_t)n * NQKV + h * HD;
    float t1 = row[lane];
    float t2 = row[lane + 64];
    float ss = t1 * t1 + t2 * t2;
#pragma unroll
    for (int o = 1; o < 64; o <<= 1) ss += __shfl_xor(ss, o);
    float r = rsqrtf(ss * (1.f / 128.f) + 1e-6f);
    float a1 = t1 * r * w[lane];
    float a2 = t2 * r * w[lane + 64];
    float freq = expf(lane * -0.14391156831212787f);
    float ang = (float)s * freq;
    float sn, cs;
    sincosf(ang, &sn, &cs);
    float o1 = a1 * cs - a2 * sn;
    float o2 = a2 * cs + a1 * sn;
    size_t base = (((size_t)(b * HH + h)) * S + s) * HD;
    dst[base + lane] = f2bf(o1);
    dst[base + 64 + lane] = f2bf(o2);
}

// ---------------- V: cast + transpose (n, 2560 + kh*D+d of qkv) fp32 -> Vt (b,kh,d,s) bf16 --
#define LDT 65
__global__ __launch_bounds__(256)
void vtrans(const float* __restrict__ src, u16* __restrict__ dst) {
    __shared__ u16 Ts[128 * LDT];
    const int t = threadIdx.x;
    const int s0 = blockIdx.x * 64;
    const int kh = blockIdx.y;
    const int b = blockIdx.z;
    const float* base = src + ((size_t)(b * S + s0)) * NQKV + 2560 + kh * HD;
#pragma unroll
    for (int i = 0; i < 8; i++) {
        int idx = i * 256 + t;
        int r = idx >> 5, c4 = (idx & 31) * 4;
        float4 v = *(const float4*)(base + (size_t)r * NQKV + c4);
        Ts[(c4 + 0) * LDT + r] = f2bf(v.x);
        Ts[(c4 + 1) * LDT + r] = f2bf(v.y);
        Ts[(c4 + 2) * LDT + r] = f2bf(v.z);
        Ts[(c4 + 3) * LDT + r] = f2bf(v.w);
    }
    __syncthreads();
    u16* obase = dst + ((size_t)(b * NKVH + kh) * HD) * S + s0;
#pragma unroll
    for (int i = 0; i < 4; i++) {
        int idx = i * 256 + t;
        int d = idx >> 3, s8 = (idx & 7) * 8;
        const u16* row = &Ts[d * LDT + s8];
        short8 o;
#pragma unroll
        for (int j = 0; j < 8; j++) o[j] = (short)row[j];
        *(short8*)(obase + (size_t)d * S + s8) = o;
    }
}

// ---------------- MFMA flash attention, 128-query blocks, XOR-swizzled LDS ----------------
// block: 128 queries x 1 head; 4 waves x 32 queries (two 16-q groups per wave)
// LDS: Ks 16KB + Vs 16KB + Ps 16KB = 49152 B -> 3 blocks/CU (LDS-limited)
// __launch_bounds__(256,2): VGPR cap 256 — R5's (256,3) cap of ~170 spilled the
// K-loop (WRITE_SIZE 16384->38400 KB scratch signature) and serialized everything.
#define KSX(key, cb) ((key) * 128 + ((((cb) ^ ((key) & 15))) * 8))
#define VSX(d, cb)   ((d) * 64 + ((((cb) ^ ((d) & 7))) * 8))
#define PSX(row, cb) ((row) * 64 + ((((cb) ^ ((row) & 7))) * 8))

__global__ __launch_bounds__(256, 2)
void attn_mfma(const u16* __restrict__ qa, const u16* __restrict__ ka,
               const u16* __restrict__ vt, u16* __restrict__ out) {
    __shared__ u16 Ks[64 * 128];
    __shared__ u16 Vs[128 * 64];
    __shared__ u16 Ps[128 * 64];
    const int tid = threadIdx.x;
    const int w = tid >> 6, lane = tid & 63;
    const int lr = lane & 15, quad = lane >> 4;
    const int qt = (int)(gridDim.x - 1) - blockIdx.x;   // heavy blocks first
    const int h = blockIdx.y, b = blockIdx.z;
    const int kh = h >> 2;
    const int q0 = qt * 128;
    const int qg0 = q0 + w * 32;          // group gi: queries qg0+gi*16 .. +15

    const float SCINV = 0.0017677669529663689f;  // 1/(sqrt(128)*50)

    short8 qf[2][4];
#pragma unroll
    for (int gi = 0; gi < 2; gi++) {
        const u16* qrow = qa + (((size_t)(b * NH + h)) * S + qg0 + gi * 16 + lr) * HD;
#pragma unroll
        for (int c = 0; c < 4; c++)
            qf[gi][c] = *(const short8*)(qrow + c * 32 + quad * 8);
    }

    f32x4 O[2][8];
#pragma unroll
    for (int gi = 0; gi < 2; gi++)
#pragma unroll
        for (int dt = 0; dt < 8; dt++) O[gi][dt] = (f32x4){0.f, 0.f, 0.f, 0.f};
    float l[2][4] = {{0.f, 0.f, 0.f, 0.f}, {0.f, 0.f, 0.f, 0.f}};

    const u16* kbase0 = ka + (((size_t)(b * NKVH + kh)) * S) * HD;
    const u16* vtbase0 = vt + ((size_t)(b * NKVH + kh) * HD) * S;

    const int jt0 = (q0 >= 1024) ? (q0 - 1024) : 0;
    const int jtend = q0 + 64;           // inclusive; upper half's diagonal tile
    for (int jt = jt0; jt <= jtend; jt += 64) {
        __syncthreads();
        const u16* kbase = kbase0 + (size_t)jt * HD;
        const u16* vtbase = vtbase0 + jt;
#pragma unroll
        for (int i = 0; i < 4; i++) {
            int idx = i * 256 + tid;
            int key = idx >> 4, cb = idx & 15;
            *(int4*)(&Ks[KSX(key, cb)]) = *(const int4*)(kbase + (size_t)key * HD + cb * 8);
            int dd = idx >> 3, cb2 = idx & 7;
            *(int4*)(&Vs[VSX(dd, cb2)]) = *(const int4*)(vtbase + (size_t)dd * S + cb2 * 8);
        }
        __syncthreads();

        u16* Pw = &Ps[w * 32 * 64];      // local rows 0..31
        bool any0 = false, any1 = false;

#pragma unroll
        for (int kt = 0; kt < 4; kt++) {
            const int keymin = jt + kt * 16;
            bool need[2], full[2];
#pragma unroll
            for (int gi = 0; gi < 2; gi++) {
                int qmin = qg0 + gi * 16, qmax = qmin + 15;
                need[gi] = (keymin <= qmax) && (keymin + 15 >= qmin - 1023);
                full[gi] = (keymin + 15 <= qmin) && (keymin >= qmax - 1023);
            }
            if (need[0] || need[1]) {
#pragma unroll
                for (int gi = 0; gi < 2; gi++) {
                    if (need[gi]) {
                        f32x4 a = (f32x4){0.f, 0.f, 0.f, 0.f};
#pragma unroll
                        for (int c = 0; c < 4; c++) {
                            short8 kf = *(const short8*)(&Ks[KSX(kt * 16 + lr, 4 * c + quad)]);
                            a = __builtin_amdgcn_mfma_f32_16x16x32_bf16(qf[gi][c], kf, a, 0, 0, 0);
                        }
#pragma unroll
                        for (int r = 0; r < 4; r++) {
                            // p = exp(sc - 50), sc = 50*tanh(x) => p = exp(-100/(e^{2x}+1))
                            float x = a[r] * SCINV;
                            float t = __expf(2.f * x);
                            float p = __expf(-100.f * __builtin_amdgcn_rcpf(t + 1.f));
                            if (!full[gi]) {
                                int rel = keymin + lr - (qg0 + gi * 16 + quad * 4 + r);
                                bool valid = (rel <= 0) && (rel > -1024);
                                p = valid ? p : 0.f;
                            }
                            l[gi][r] += p;
                            Pw[PSX(gi * 16 + quad * 4 + r, kt * 2 + (lr >> 3)) + (lr & 7)] =
                                (u16)(__float_as_uint(p) >> 16);
                        }
                        if (gi == 0) any0 = true; else any1 = true;
                    } else {
#pragma unroll
                        for (int r = 0; r < 4; r++)
                            Pw[PSX(gi * 16 + quad * 4 + r, kt * 2 + (lr >> 3)) + (lr & 7)] = 0;
                    }
                }
            } else {
#pragma unroll
                for (int gi = 0; gi < 2; gi++)
#pragma unroll
                    for (int r = 0; r < 4; r++)
                        Pw[PSX(gi * 16 + quad * 4 + r, kt * 2 + (lr >> 3)) + (lr & 7)] = 0;
            }
        }

        // PV: O[q][d] += P[q][key] * Vt[d][key]
        // dt outer so vf is a single live short8 (shared across both q-groups)
        if (any0 || any1) {
#pragma unroll
            for (int c2 = 0; c2 < 2; c2++) {
                short8 pf0 = *(const short8*)(&Pw[PSX(lr, c2 * 4 + quad)]);
                short8 pf1 = *(const short8*)(&Pw[PSX(16 + lr, c2 * 4 + quad)]);
#pragma unroll
                for (int dt = 0; dt < 8; dt++) {
                    short8 vf = *(const short8*)(&Vs[VSX(dt * 16 + lr, c2 * 4 + quad)]);
                    if (any0)
                        O[0][dt] = __builtin_amdgcn_mfma_f32_16x16x32_bf16(pf0, vf, O[0][dt], 0, 0, 0);
                    if (any1)
                        O[1][dt] = __builtin_amdgcn_mfma_f32_16x16x32_bf16(pf1, vf, O[1][dt], 0, 0, 0);
                }
            }
        }
    }

#pragma unroll
    for (int gi = 0; gi < 2; gi++)
#pragma unroll
        for (int r = 0; r < 4; r++) {
            l[gi][r] += __shfl_xor(l[gi][r], 1);
            l[gi][r] += __shfl_xor(l[gi][r], 2);
            l[gi][r] += __shfl_xor(l[gi][r], 4);
            l[gi][r] += __shfl_xor(l[gi][r], 8);
        }
#pragma unroll
    for (int gi = 0; gi < 2; gi++)
#pragma unroll
        for (int r = 0; r < 4; r++) {
            float inv = 1.f / l[gi][r];
            u16* orow = out + ((size_t)(b * S + qg0 + gi * 16 + quad * 4 + r)) * E + h * HD;
#pragma unroll
            for (int dt = 0; dt < 8; dt++)
                orow[dt * 16 + lr] = f2bf(O[gi][dt][r] * inv);
        }
}

// ---------------- residual + LayerNorm ----------------
__global__ __launch_bounds__(256)
void ln_kernel(const float* __restrict__ x, const float* __restrict__ pr,
               const float* __restrict__ g, const float* __restrict__ be,
               float* __restrict__ out) {
    int n = blockIdx.x;
    int tid = threadIdx.x;
    const float* xr = x + (size_t)n * E;
    const float* p = pr + (size_t)n * E;
    float y[8];
    float s = 0.f, ss = 0.f;
#pragma unroll
    for (int i = 0; i < 2; i++) {
        float4 a = *(const float4*)(xr + tid * 8 + i * 4);
        float4 b = *(const float4*)(p + tid * 8 + i * 4);
        float v0 = a.x + b.x, v1 = a.y + b.y, v2 = a.z + b.z, v3 = a.w + b.w;
        y[i * 4 + 0] = v0; y[i * 4 + 1] = v1; y[i * 4 + 2] = v2; y[i * 4 + 3] = v3;
        s += v0 + v1 + v2 + v3;
        ss += v0 * v0 + v1 * v1 + v2 * v2 + v3 * v3;
    }
#pragma unroll
    for (int o = 1; o < 64; o <<= 1) {
        s += __shfl_xor(s, o);
        ss += __shfl_xor(ss, o);
    }
    __shared__ float r0[4], r1[4];
    int w = tid >> 6;
    if ((tid & 63) == 0) { r0[w] = s; r1[w] = ss; }
    __syncthreads();
    s = r0[0] + r0[1] + r0[2] + r0[3];
    ss = r1[0] + r1[1] + r1[2] + r1[3];
    float mu = s * (1.f / 2048.f);
    float var = ss * (1.f / 2048.f) - mu * mu;
    float rs = rsqrtf(var + 1e-5f);
    float* orow = out + (size_t)n * E;
#pragma unroll
    for (int i = 0; i < 8; i++) {
        int c = tid * 8 + i;
        orow[c] = (y[i] - mu) * rs * g[c] + be[c];
    }
}

// ---------------- launch ----------------
extern "C" void kernel_launch(void* const* d_in, const int* in_sizes, int n_in,
                              void* d_out, int out_size, void* d_ws, size_t ws_size,
                              hipStream_t stream) {
    (void)in_sizes; (void)n_in; (void)out_size; (void)ws_size;
    const float* x   = (const float*)d_in[0];
    const float* Wq  = (const float*)d_in[1];
    const float* Wk  = (const float*)d_in[2];
    const float* Wv  = (const float*)d_in[3];
    const float* Wo  = (const float*)d_in[4];
    const float* qnw = (const float*)d_in[5];
    const float* knw = (const float*)d_in[6];
    const float* lng = (const float*)d_in[7];
    const float* lnb = (const float*)d_in[8];
    float* out = (float*)d_out;

    char* ws = (char*)d_ws;
    size_t off = 0;
    auto alloc = [&](size_t bytes) -> char* {
        char* pp = ws + off;
        off = (off + bytes + 255) & ~(size_t)255;
        return pp;
    };
    u16*  xb     = (u16*)alloc((size_t)NTOK * E * 2);       // later reused as attn_out
    u16*  Wqkvb  = (u16*)alloc((size_t)NQKV * E * 2);       // [Wq; Wk; Wv]
    u16*  Wob    = (u16*)alloc((size_t)E * E * 2);
    float* qkvraw= (float*)alloc((size_t)NTOK * NQKV * 4);  // later reused as proj
    u16*  qaa    = (u16*)alloc((size_t)NTOK * E * 2);
    u16*  kaa    = (u16*)alloc((size_t)NTOK * 512 * 2);
    u16*  vtt    = (u16*)alloc((size_t)NTOK * 512 * 2);
    u16*  attn_o = xb;
    float* proj  = qkvraw;

    cast5<<<dim3(18432), 256, 0, stream>>>(x, Wq, Wk, Wv, Wo, xb, Wqkvb, Wob);

    gemm_bt<<<dim3(NQKV / TN, NTOK / TM), 256, 0, stream>>>(xb, Wqkvb, qkvraw, NTOK, NQKV, E);

    rmsrope2<<<dim3((NTOK * NH + NTOK * NKVH) / 4), 256, 0, stream>>>(
        qkvraw, qnw, knw, qaa, kaa);
    vtrans<<<dim3(S / 64, NKVH, 2), 256, 0, stream>>>(qkvraw, vtt);

    attn_mfma<<<dim3(S / 128, NH, 2), 256, 0, stream>>>(qaa, kaa, vtt, attn_o);

    gemm_bt<<<dim3(E / TN, NTOK / TM), 256, 0, stream>>>(attn_o, Wob, proj, NTOK, E, E);

    ln_kernel<<<dim3(NTOK), 256, 0, stream>>>(x, proj, lng, lnb, out);
}